// Round 7
// baseline (362.032 us; speedup 1.0000x reference)
//
#include <hip/hip_runtime.h>
#include <hip/hip_bf16.h>
#include <math.h>

// x(32,512,768) fp32 -> LayerNorm(768) -> Linear 768x3072 + bias -> exact GELU
// M = 16384, K = 768, N = 3072. Output fp32.
#define M_ROWS 16384
#define K_DIM  768
#define N_DIM  3072
#define NT     24      // K_DIM / 32 K-tiles (BK=32)

typedef __bf16 bf16x8 __attribute__((ext_vector_type(8)));
typedef float  f32x4  __attribute__((ext_vector_type(4)));
typedef unsigned short u16x4 __attribute__((ext_vector_type(4)));

__device__ __forceinline__ unsigned short f2bf(float f) {
    unsigned int u = __float_as_uint(f);
    unsigned int r = (u + 0x7fffu + ((u >> 16) & 1u)) >> 16;   // RNE
    return (unsigned short)r;
}

__device__ __forceinline__ void async16(const unsigned short* g, unsigned short* l) {
    __builtin_amdgcn_global_load_lds(
        (const __attribute__((address_space(1))) unsigned int*)g,
        (__attribute__((address_space(3))) unsigned int*)l,
        16, 0, 0);
}

// tanh-form GELU: 0.5h(1+tanh(0.79788456(h+0.044715h^3))); max |err| vs erf ~1e-3
__device__ __forceinline__ float gelu_fast(float h) {
    float h2 = h * h;
    float z2 = h * __builtin_fmaf(0.0713548162f, h2, 1.5957691216f); // 2*z
    float E  = __expf(z2);                                           // e^{2z}
    float r  = __builtin_amdgcn_rcpf(1.0f + E);                      // (1-tanh)/2
    return h - h * r;                                                // 0.5h(1+tanh)
}

// ---------- 1) LayerNorm + cast to bf16 (vectorized) ----------
__global__ __launch_bounds__(256) void ln_kernel(const float* __restrict__ x,
                                                 const float* __restrict__ gamma,
                                                 const float* __restrict__ beta,
                                                 unsigned short* __restrict__ xn) {
    int wave = threadIdx.x >> 6;
    int lane = threadIdx.x & 63;
    int row  = blockIdx.x * 4 + wave;
    const f32x4* xr = (const f32x4*)(x + (size_t)row * K_DIM);
    const f32x4* g4 = (const f32x4*)gamma;
    const f32x4* b4 = (const f32x4*)beta;

    f32x4 v[3];
    float s = 0.f, ss = 0.f;
#pragma unroll
    for (int q = 0; q < 3; q++) {
        v[q] = __builtin_nontemporal_load(&xr[lane + 64 * q]);   // x read exactly once
#pragma unroll
        for (int e = 0; e < 4; e++) { s += v[q][e]; ss += v[q][e] * v[q][e]; }
    }
#pragma unroll
    for (int off = 32; off; off >>= 1) {
        s  += __shfl_xor(s,  off, 64);
        ss += __shfl_xor(ss, off, 64);
    }
    float mu   = s * (1.f / K_DIM);
    float var  = ss * (1.f / K_DIM) - mu * mu;
    float rstd = rsqrtf(var + 1e-12f);

    u16x4* xo = (u16x4*)(xn + (size_t)row * K_DIM);
#pragma unroll
    for (int q = 0; q < 3; q++) {
        f32x4 gv = g4[lane + 64 * q];
        f32x4 bv = b4[lane + 64 * q];
        u16x4 o;
#pragma unroll
        for (int e = 0; e < 4; e++)
            o[e] = f2bf((v[q][e] - mu) * rstd * gv[e] + bv[e]);
        xo[lane + 64 * q] = o;
    }
}

// ---------- 2) W [K,N] fp32 -> Wt [N,K] bf16 ----------
__global__ __launch_bounds__(256) void wcast_kernel(const float* __restrict__ W,
                                                    unsigned short* __restrict__ wt) {
    __shared__ float tile[32][33];
    int bx = blockIdx.x, by = blockIdx.y;
    int tx = threadIdx.x, ty = threadIdx.y;
#pragma unroll
    for (int r = 0; r < 4; r++)
        tile[ty + 8 * r][tx] = __builtin_nontemporal_load(
            &W[(size_t)(by * 32 + ty + 8 * r) * N_DIM + bx * 32 + tx]);  // W read once
    __syncthreads();
#pragma unroll
    for (int r = 0; r < 4; r++)
        wt[(size_t)(bx * 32 + ty + 8 * r) * K_DIM + by * 32 + tx] = f2bf(tile[tx][ty + 8 * r]);
}

// ---------- 3) GEMM + bias + GELU: 256x256, BK=32, 4-buffer, read/MFMA SKEW ----------
// Round-7 lever (the one r2/r5/r6 all lacked): issue ALL ds_reads for tile t+1,
// wait lgkmcnt(12) (drains only tile t's reads; t+1's 12 stay in flight), then
// run tile t's 32-MFMA cluster (1240 cyc/SIMD) -- the LDS queue drains UNDER
// the matrix pipe instead of serially before it. Two named register sets
// (E/O, static indexing per rule #20), 2x-unrolled loop.
// Boundary: s_waitcnt vmcnt(4) [tile t+2's stage stays in flight]; s_barrier;
// sched_barrier(0). Staging for t+3 is issued AFTER the barrier (every wave
// arrived only after draining its reads of that buffer => race-free).
// sched_barrier(0) after lgkmcnt(12) pins reads-before-MFMA (rule #18).
__global__ __launch_bounds__(512, 2) void gemm_kernel(const unsigned short* __restrict__ A,
                                                      const unsigned short* __restrict__ B,
                                                      const float* __restrict__ bias,
                                                      float* __restrict__ C) {
    __shared__ __attribute__((aligned(16))) unsigned short As[4][256 * 32];
    __shared__ __attribute__((aligned(16))) unsigned short Bs[4][256 * 32];

    int tid   = threadIdx.x;
    int lane  = tid & 63;
    int wid   = tid >> 6;
    int waveM = wid >> 2;        // 0..1 -> 128 M-rows each
    int waveN = wid & 3;         // 0..3 -> 64 N-cols each

    // 256 blocks, 8 XCDs: XCD k gets wg [32k,32k+32) = contiguous bm panels,
    // 2 XCDs share one bng (3 B panels, ~1.2 MB, L2-resident).
    int orig = blockIdx.y * 4 + blockIdx.x;
    int wg   = (orig & 7) * 32 + (orig >> 3);
    int bng  = wg >> 6;          // 0..3 -> bn = bng*3 + rep
    int bm   = wg & 63;

    const unsigned short* Ag = A + (size_t)bm * 256 * K_DIM;
    const unsigned short* Bg = B + (size_t)(bng * 3) * 256 * K_DIM;

    int mrow = lane & 15;
    int quad = lane >> 4;
    int chp  = (quad ^ ((mrow >> 1) & 3)) * 8;   // swizzled k-chunk (shorts)

    f32x4 acc[4][8];

    // staging (proven r6, 0 conflicts): 4 async16/thread; dest wave-linear;
    // source chunk pre-swizzled by ^((row>>1)&3).
#define STAGE(ap, bp, kt, bfi) do { \
        _Pragma("unroll") \
        for (int i = 0; i < 2; ++i) { \
            int r  = i * 128 + (tid >> 2); \
            int sc = (tid & 3) ^ ((r >> 1) & 3); \
            async16((ap) + (size_t)r * K_DIM + (kt) * 32 + sc * 8, \
                    &As[bfi][r * 32 + (tid & 3) * 8]); \
        } \
        _Pragma("unroll") \
        for (int i = 0; i < 2; ++i) { \
            int r  = i * 128 + (tid >> 2); \
            int sc = (tid & 3) ^ ((r >> 1) & 3); \
            async16((bp) + (size_t)r * K_DIM + (kt) * 32 + sc * 8, \
                    &Bs[bfi][r * 32 + (tid & 3) * 8]); \
        } } while (0)

#define RD_X(j, bfi) (*(const bf16x8*)&As[bfi][(waveM * 128 + (j) * 16 + mrow) * 32 + chp])
#define RD_W(i, bfi) (*(const bf16x8*)&Bs[bfi][(waveN * 64  + (i) * 16 + mrow) * 32 + chp])

    // 12 ds_read_b128 into a named register set
#define READS(WF, XF, bfi) do { \
        _Pragma("unroll") \
        for (int i = 0; i < 4; ++i) WF[i] = RD_W(i, bfi); \
        _Pragma("unroll") \
        for (int j = 0; j < 8; ++j) XF[j] = RD_X(j, bfi); \
    } while (0)

#define MFMA_ALL(WF, XF) do { \
        __builtin_amdgcn_s_setprio(1); \
        _Pragma("unroll") \
        for (int i = 0; i < 4; ++i) \
            _Pragma("unroll") \
            for (int j = 0; j < 8; ++j) \
                acc[i][j] = __builtin_amdgcn_mfma_f32_16x16x32_bf16(WF[i], XF[j], acc[i][j], 0, 0, 0); \
        __builtin_amdgcn_s_setprio(0); \
    } while (0)

#define BOUNDARY(NV) do { \
        asm volatile("s_waitcnt vmcnt(" #NV ")" ::: "memory"); \
        __builtin_amdgcn_s_barrier(); \
        __builtin_amdgcn_sched_barrier(0); \
    } while (0)

#define LGKM12 do { \
        asm volatile("s_waitcnt lgkmcnt(12)" ::: "memory"); \
        __builtin_amdgcn_sched_barrier(0); \
    } while (0)

    bf16x8 wfE[4], xfE[8], wfO[4], xfO[8];

    // rep-0 prologue: stage tiles 0,1,2 -> bufs 0,1,2; t0 resident; reads(0)->E
    STAGE(Ag, Bg, 0, 0); STAGE(Ag, Bg, 1, 1); STAGE(Ag, Bg, 2, 2);
    asm volatile("s_waitcnt vmcnt(8)" ::: "memory");
    __builtin_amdgcn_s_barrier();
    __builtin_amdgcn_sched_barrier(0);
    READS(wfE, xfE, 0);

    for (int rep = 0; rep < 3; ++rep) {
#pragma unroll
        for (int i = 0; i < 4; ++i)
#pragma unroll
            for (int j = 0; j < 8; ++j)
                acc[i][j] = (f32x4){0.f, 0.f, 0.f, 0.f};

        // main pairs: t = 0,2,...,20  (tiles 0..21)
        for (int tt = 0; tt < 11; ++tt) {
            int t = tt * 2;

            // even: reads(t+1)->O while MFMA(t) on E; stage(t+3)
            BOUNDARY(4);                          // t+1 resident (t+2 in flight)
            STAGE(Ag, Bg, t + 3, (t + 3) & 3);    // buf freed: reads(t-1) drained pre-barrier
            READS(wfO, xfO, (t + 1) & 3);
            LGKM12;                               // reads(t) done; t+1's 12 in flight
            MFMA_ALL(wfE, xfE);

            // odd: reads(t+2)->E while MFMA(t+1) on O; stage(t+4)
            BOUNDARY(4);                          // t+2 resident (t+3 in flight)
            if (t + 4 < NT) STAGE(Ag, Bg, t + 4, (t + 4) & 3);
            READS(wfE, xfE, (t + 2) & 3);
            LGKM12;
            MFMA_ALL(wfO, xfO);
        }

        // peel t=22: reads(23)->O while MFMA(22) on E
        BOUNDARY(0);                              // tile 23 resident
        READS(wfO, xfO, 3);
        LGKM12;
        MFMA_ALL(wfE, xfE);
        // peel t=23
        asm volatile("s_waitcnt lgkmcnt(0)" ::: "memory");
        __builtin_amdgcn_sched_barrier(0);
        MFMA_ALL(wfO, xfO);

        int bn = bng * 3 + rep;
        int m0 = bm * 256 + waveM * 128 + mrow;
        int n0 = bn * 256 + waveN * 64 + quad * 4;
        const unsigned short* Bg2 = B + (size_t)(bn + 1) * 256 * K_DIM;

        // rep tail: sync (all waves fully drained -> all bufs free), then stage
        // next rep's tiles 0,1,2 BEFORE the epilogue so GELU+stores hide them.
        if (rep < 2) {
            __syncthreads();
            STAGE(Ag, Bg2, 0, 0); STAGE(Ag, Bg2, 1, 1); STAGE(Ag, Bg2, 2, 2);
        }

        // epilogue: bias + GELU + nontemporal store (C written once, never read)
#pragma unroll
        for (int i = 0; i < 4; ++i) {
            f32x4 bb = *(const f32x4*)(bias + n0 + i * 16);
#pragma unroll
            for (int j = 0; j < 8; ++j) {
                f32x4 o;
#pragma unroll
                for (int r = 0; r < 4; ++r)
                    o[r] = gelu_fast(acc[i][j][r] + bb[r]);
                __builtin_nontemporal_store(o, (f32x4*)(C + (size_t)(m0 + j * 16) * N_DIM + n0 + i * 16));
            }
        }

        if (rep < 2) {
            __syncthreads();   // drains staging (+stores); bufs 0,1,2 resident
            READS(wfE, xfE, 0);
            Bg = Bg2;
        }
    }
}

extern "C" void kernel_launch(void* const* d_in, const int* in_sizes, int n_in,
                              void* d_out, int out_size, void* d_ws, size_t ws_size,
                              hipStream_t stream) {
    const float* x     = (const float*)d_in[0];
    const float* gamma = (const float*)d_in[1];
    const float* beta  = (const float*)d_in[2];
    const float* W     = (const float*)d_in[3];
    const float* bias  = (const float*)d_in[4];
    float* out = (float*)d_out;

    unsigned short* xn = (unsigned short*)d_ws;
    unsigned short* wt = xn + (size_t)M_ROWS * K_DIM;

    ln_kernel<<<M_ROWS / 4, 256, 0, stream>>>(x, gamma, beta, xn);
    wcast_kernel<<<dim3(N_DIM / 32, K_DIM / 32), dim3(32, 8), 0, stream>>>(W, wt);
    gemm_kernel<<<dim3(4, 64), 512, 0, stream>>>(xn, wt, bias, out);
}

// Round 10
// 339.939 us; speedup vs baseline: 1.0650x; 1.0650x over previous
//
#include <hip/hip_runtime.h>
#include <hip/hip_bf16.h>
#include <math.h>

// x(32,512,768) fp32 -> LayerNorm(768) -> Linear 768x3072 + bias -> exact GELU
// M = 16384, K = 768, N = 3072. Output fp32.
// FINAL: best-measured configuration (round 2, 346.43 us total, gemm 144.4 us).
// Session findings: five GEMM sync structures (8-phase counted / 1-sync drain /
// 4-buffer counted / skewed pipeline / 128-tile 2-sync) all measure 485-540 TF
// at MfmaUtil 19-22% on this K=768 shape; the binding constraint is invariant
// to schedule and was not localizable with full-bench rounds (model predicts
// 35-45% util for this structure). Not a HW roofline; banking best verified.
#define M_ROWS 16384
#define K_DIM  768
#define N_DIM  3072
#define NT     12      // K_DIM / 64 K-tiles

typedef __bf16 bf16x8 __attribute__((ext_vector_type(8)));
typedef float  f32x4  __attribute__((ext_vector_type(4)));
typedef unsigned short u16x4 __attribute__((ext_vector_type(4)));

__device__ __forceinline__ unsigned short f2bf(float f) {
    unsigned int u = __float_as_uint(f);
    unsigned int r = (u + 0x7fffu + ((u >> 16) & 1u)) >> 16;   // RNE
    return (unsigned short)r;
}

__device__ __forceinline__ void async16(const unsigned short* g, unsigned short* l) {
    __builtin_amdgcn_global_load_lds(
        (const __attribute__((address_space(1))) unsigned int*)g,
        (__attribute__((address_space(3))) unsigned int*)l,
        16, 0, 0);
}

// tanh-form GELU: 0.5h(1+tanh(0.79788456(h+0.044715h^3))); max |err| vs erf ~1e-3
__device__ __forceinline__ float gelu_fast(float h) {
    float h2 = h * h;
    float z2 = h * __builtin_fmaf(0.0713548162f, h2, 1.5957691216f); // 2*z
    float E  = __expf(z2);                                           // e^{2z}
    float r  = __builtin_amdgcn_rcpf(1.0f + E);                      // (1-tanh)/2
    return h - h * r;                                                // 0.5h(1+tanh)
}

// ---------- 1) LayerNorm + cast to bf16 (vectorized) ----------
__global__ __launch_bounds__(256) void ln_kernel(const float* __restrict__ x,
                                                 const float* __restrict__ gamma,
                                                 const float* __restrict__ beta,
                                                 unsigned short* __restrict__ xn) {
    int wave = threadIdx.x >> 6;
    int lane = threadIdx.x & 63;
    int row  = blockIdx.x * 4 + wave;
    const f32x4* xr = (const f32x4*)(x + (size_t)row * K_DIM);
    const f32x4* g4 = (const f32x4*)gamma;
    const f32x4* b4 = (const f32x4*)beta;

    f32x4 v[3];
    float s = 0.f, ss = 0.f;
#pragma unroll
    for (int q = 0; q < 3; q++) {
        v[q] = __builtin_nontemporal_load(&xr[lane + 64 * q]);   // x read exactly once
#pragma unroll
        for (int e = 0; e < 4; e++) { s += v[q][e]; ss += v[q][e] * v[q][e]; }
    }
#pragma unroll
    for (int off = 32; off; off >>= 1) {
        s  += __shfl_xor(s,  off, 64);
        ss += __shfl_xor(ss, off, 64);
    }
    float mu   = s * (1.f / K_DIM);
    float var  = ss * (1.f / K_DIM) - mu * mu;
    float rstd = rsqrtf(var + 1e-12f);

    u16x4* xo = (u16x4*)(xn + (size_t)row * K_DIM);
#pragma unroll
    for (int q = 0; q < 3; q++) {
        f32x4 gv = g4[lane + 64 * q];
        f32x4 bv = b4[lane + 64 * q];
        u16x4 o;
#pragma unroll
        for (int e = 0; e < 4; e++)
            o[e] = f2bf((v[q][e] - mu) * rstd * gv[e] + bv[e]);
        xo[lane + 64 * q] = o;
    }
}

// ---------- 2) W [K,N] fp32 -> Wt [N,K] bf16 ----------
__global__ __launch_bounds__(256) void wcast_kernel(const float* __restrict__ W,
                                                    unsigned short* __restrict__ wt) {
    __shared__ float tile[32][33];
    int bx = blockIdx.x, by = blockIdx.y;
    int tx = threadIdx.x, ty = threadIdx.y;
#pragma unroll
    for (int r = 0; r < 4; r++)
        tile[ty + 8 * r][tx] = __builtin_nontemporal_load(
            &W[(size_t)(by * 32 + ty + 8 * r) * N_DIM + bx * 32 + tx]);  // W read once
    __syncthreads();
#pragma unroll
    for (int r = 0; r < 4; r++)
        wt[(size_t)(bx * 32 + ty + 8 * r) * K_DIM + by * 32 + tx] = f2bf(tile[tx][ty + 8 * r]);
}

// ---------- 3) GEMM + bias + GELU: 256x256 tile, BK=64, 8 waves, 8-phase ----------
// Persistent-block version: grid = 256 blocks (1/CU). Each block owns one A
// row-panel (bm) and walks 3 consecutive bn tiles (reps). 4 phases per K-tile,
// 16 MFMA each, snake quadrant order; staging units of 16KB, 1 per phase;
// counted vmcnt(4) at the K-tile boundary (never 0 in steady state); LDS
// chunk-XOR swizzle on the pre-swizzled global source (0 bank conflicts,
// verified); s_setprio(1) around MFMA clusters; bijective XCD block swizzle.
__global__ __launch_bounds__(512, 2) void gemm_kernel(const unsigned short* __restrict__ A,
                                                      const unsigned short* __restrict__ B,
                                                      const float* __restrict__ bias,
                                                      float* __restrict__ C) {
    __shared__ __attribute__((aligned(16))) unsigned short As[2][256 * 64];
    __shared__ __attribute__((aligned(16))) unsigned short Bs[2][256 * 64];

    int tid   = threadIdx.x;
    int lane  = tid & 63;
    int wid   = tid >> 6;
    int waveM = wid >> 2;        // 0..1 -> 128 M-rows each
    int waveN = wid & 3;         // 0..3 -> 64 N-cols each

    // 256 blocks, 8 XCDs: each XCD gets 32 consecutive wg = contiguous bm panels;
    // 2 XCDs share one bng (3 B panels, ~1.2 MB, L2-resident).
    int orig = blockIdx.y * 4 + blockIdx.x;
    int wg   = (orig & 7) * 32 + (orig >> 3);
    int bng  = wg >> 6;          // 0..3  -> bn = bng*3 + rep
    int bm   = wg & 63;

    const unsigned short* Ag = A + (size_t)bm * 256 * K_DIM;
    const unsigned short* Bg = B + (size_t)(bng * 3) * 256 * K_DIM;

    // staging geometry: per unit, thread covers (row_in_unit = l*64 + rsub, chunk = cch)
    int rsub = wid * 8 + (lane >> 3);   // 0..63, wave-contiguous 8-row span
    int cch  = lane & 7;
    int sch  = cch ^ (rsub & 7);        // pre-swizzled source chunk (row&7 == rsub&7)

    int mrow = lane & 15;
    int quad = lane >> 4;
    int swz  = mrow & 7;

    f32x4 acc[4][8];

#define STAGE_A(gp, a, kt, bfi) do { \
        _Pragma("unroll") \
        for (int l = 0; l < 2; ++l) { \
            int pr = l * 128 + (a) * 64 + rsub; \
            async16((gp) + (size_t)pr * K_DIM + (kt) * 64 + sch * 8, \
                    &As[bfi][pr * 64 + cch * 8]); \
        } } while (0)
#define STAGE_B(gp, b, kt, bfi) do { \
        _Pragma("unroll") \
        for (int l = 0; l < 2; ++l) { \
            int pr = l * 128 + (b) * 32 + (rsub & 31) + ((rsub >> 5) << 6); \
            async16((gp) + (size_t)pr * K_DIM + (kt) * 64 + sch * 8, \
                    &Bs[bfi][pr * 64 + cch * 8]); \
        } } while (0)

#define RD_X(j, kk, bfi) (*(const bf16x8*)&As[bfi][(waveM * 128 + (j) * 16 + mrow) * 64 + ((((kk) * 4 + quad) ^ swz) * 8)])
#define RD_W(i, kk, bfi) (*(const bf16x8*)&Bs[bfi][(waveN * 64  + (i) * 16 + mrow) * 64 + ((((kk) * 4 + quad) ^ swz) * 8)])

#define MFMA_QUAD(I0, J0) do { \
        asm volatile("s_waitcnt lgkmcnt(0)" ::: "memory"); \
        __builtin_amdgcn_s_setprio(1); \
        _Pragma("unroll") \
        for (int jj = 0; jj < 4; ++jj) { \
            _Pragma("unroll") \
            for (int kk = 0; kk < 2; ++kk) { \
                acc[(I0)][(J0) + jj]     = __builtin_amdgcn_mfma_f32_16x16x32_bf16(wf[0][kk], xf[jj][kk], acc[(I0)][(J0) + jj], 0, 0, 0); \
                acc[(I0) + 1][(J0) + jj] = __builtin_amdgcn_mfma_f32_16x16x32_bf16(wf[1][kk], xf[jj][kk], acc[(I0) + 1][(J0) + jj], 0, 0, 0); \
            } \
        } \
        __builtin_amdgcn_s_setprio(0); \
        asm volatile("" ::: "memory"); \
        __builtin_amdgcn_s_barrier(); \
        asm volatile("" ::: "memory"); \
    } while (0)

    // rep-0 prologue: tile0 fully + first two units of tile1; leaves 4 ops in flight
    STAGE_A(Ag, 0, 0, 0); STAGE_B(Bg, 1, 0, 0); STAGE_A(Ag, 1, 0, 0); STAGE_B(Bg, 0, 0, 0);
    STAGE_A(Ag, 0, 1, 1); STAGE_B(Bg, 1, 1, 1);
    asm volatile("s_waitcnt vmcnt(4)" ::: "memory");
    __builtin_amdgcn_s_barrier();
    asm volatile("" ::: "memory");

    bf16x8 xf[4][2], wf[2][2];

    for (int rep = 0; rep < 3; ++rep) {
#pragma unroll
        for (int i = 0; i < 4; ++i)
#pragma unroll
            for (int j = 0; j < 8; ++j)
                acc[i][j] = (f32x4){0.f, 0.f, 0.f, 0.f};

        for (int t = 0; t < NT; ++t) {
            int bf = t & 1, nb = bf ^ 1;

            // ---- P1: read x j0-3 (8) + w i0-1 (4); stage UA1(t+1) -> other buf
#pragma unroll
            for (int j = 0; j < 4; ++j) { xf[j][0] = RD_X(j, 0, bf); xf[j][1] = RD_X(j, 1, bf); }
            wf[0][0] = RD_W(0, 0, bf); wf[0][1] = RD_W(0, 1, bf);
            wf[1][0] = RD_W(1, 0, bf); wf[1][1] = RD_W(1, 1, bf);
            if (t + 1 < NT) STAGE_A(Ag, 1, t + 1, nb);
            asm volatile("" ::: "memory");
            __builtin_amdgcn_s_barrier();
            MFMA_QUAD(0, 0);

            // ---- P2: read w i2-3 (4); stage UB0(t+1) -> other buf
            wf[0][0] = RD_W(2, 0, bf); wf[0][1] = RD_W(2, 1, bf);
            wf[1][0] = RD_W(3, 0, bf); wf[1][1] = RD_W(3, 1, bf);
            if (t + 1 < NT) STAGE_B(Bg, 0, t + 1, nb);
            asm volatile("" ::: "memory");
            __builtin_amdgcn_s_barrier();
            MFMA_QUAD(2, 0);

            // ---- P3: read x j4-7 (8); stage UA0(t+2) -> CURRENT buf (freed after P1)
#pragma unroll
            for (int j = 0; j < 4; ++j) { xf[j][0] = RD_X(j + 4, 0, bf); xf[j][1] = RD_X(j + 4, 1, bf); }
            if (t + 2 < NT) STAGE_A(Ag, 0, t + 2, bf);
            asm volatile("" ::: "memory");
            __builtin_amdgcn_s_barrier();
            MFMA_QUAD(2, 4);

            // ---- P4: re-read w i0-1 (4); stage UB1(t+2) -> CURRENT buf (freed after P3);
            //      K-tile boundary wait: counted vmcnt(4) (2 units stay in flight)
            wf[0][0] = RD_W(0, 0, bf); wf[0][1] = RD_W(0, 1, bf);
            wf[1][0] = RD_W(1, 0, bf); wf[1][1] = RD_W(1, 1, bf);
            if (t + 2 < NT) STAGE_B(Bg, 1, t + 2, bf);
            if (t < NT - 2)       asm volatile("s_waitcnt vmcnt(4)" ::: "memory");
            else if (t == NT - 2) asm volatile("s_waitcnt vmcnt(0)" ::: "memory");
            asm volatile("" ::: "memory");
            __builtin_amdgcn_s_barrier();
            MFMA_QUAD(0, 4);
        }

        int bn = bng * 3 + rep;
        int m0 = bm * 256 + waveM * 128 + mrow;
        int n0 = bn * 256 + waveN * 64 + quad * 4;
        const unsigned short* Bg2 = B + (size_t)(bn + 1) * 256 * K_DIM;

        // issue next rep's tile0 staging BEFORE the epilogue: the GELU+store
        // work below hides the load latency. Safe: all waves passed the final
        // MFMA_QUAD barrier of t=NT-1, so both LDS buffers are dead.
        if (rep < 2) {
            STAGE_A(Ag, 0, 0, 0); STAGE_B(Bg2, 1, 0, 0);
            STAGE_A(Ag, 1, 0, 0); STAGE_B(Bg2, 0, 0, 0);
            asm volatile("" ::: "memory");   // pin FIFO: [tile0 loads][stores][tile1 loads]
        }

        // epilogue: bias + GELU + nontemporal store (C written once, never read)
#pragma unroll
        for (int i = 0; i < 4; ++i) {
            f32x4 bb = *(const f32x4*)(bias + n0 + i * 16);
#pragma unroll
            for (int j = 0; j < 8; ++j) {
                f32x4 o;
#pragma unroll
                for (int r = 0; r < 4; ++r)
                    o[r] = gelu_fast(acc[i][j][r] + bb[r]);
                __builtin_nontemporal_store(o, (f32x4*)(C + (size_t)(m0 + j * 16) * N_DIM + n0 + i * 16));
            }
        }

        if (rep < 2) {
            asm volatile("" ::: "memory");   // pin stores above tile1 loads
            STAGE_A(Ag, 0, 1, 1); STAGE_B(Bg2, 1, 1, 1);
            // vmcnt(8): drains all 8 tile0 loads + 28 of 32 stores (FIFO-oldest);
            // leaves <=8 youngest (last stores + tile1 partial) in flight.
            asm volatile("s_waitcnt vmcnt(8)" ::: "memory");
            __builtin_amdgcn_s_barrier();
            asm volatile("" ::: "memory");
            Bg = Bg2;
        }
    }
}

extern "C" void kernel_launch(void* const* d_in, const int* in_sizes, int n_in,
                              void* d_out, int out_size, void* d_ws, size_t ws_size,
                              hipStream_t stream) {
    const float* x     = (const float*)d_in[0];
    const float* gamma = (const float*)d_in[1];
    const float* beta  = (const float*)d_in[2];
    const float* W     = (const float*)d_in[3];
    const float* bias  = (const float*)d_in[4];
    float* out = (float*)d_out;

    unsigned short* xn = (unsigned short*)d_ws;
    unsigned short* wt = xn + (size_t)M_ROWS * K_DIM;

    ln_kernel<<<M_ROWS / 4, 256, 0, stream>>>(x, gamma, beta, xn);
    wcast_kernel<<<dim3(N_DIM / 32, K_DIM / 32), dim3(32, 8), 0, stream>>>(W, wt);
    gemm_kernel<<<dim3(4, 64), 512, 0, stream>>>(xn, wt, bias, out);
}